// Round 1
// baseline (378.183 us; speedup 1.0000x reference)
//
#include <hip/hip_runtime.h>
#include <math.h>

#define NB 32
#define SEQT 512
#define DDIM 16
#define NWIN 510              // SEQT - L
#define NTOT (NB*NWIN)        // 16320
#define HH 64
#define INF 33                // L*D + 1
#define SLOPE 0.2f
#define BLK 256
#define NCHUNK 64             // ceil(16320/256)

// ws layout (floats)
#define WT0_SZ (DDIM*INF*HH)  // 33792
#define WT1_SZ (DDIM*HH*HH)   // 65536
#define WT2_SZ (DDIM*HH*HH)   // 65536
#define WT0_OFF 0
#define WT1_OFF (WT0_OFF+WT0_SZ)
#define WT2_OFF (WT1_OFF+WT1_SZ)
#define RED_OFF (WT2_OFF+WT2_SZ)   // 164864
#define RED_SZ (DDIM*NCHUNK*2)     // 2048

// Transpose weights so the contracted index is the slow one:
// Wt0[d][i][h] = W0[d][h][i], Wt1[d][h_in][k] = W1[d][k][h_in], same for W2.
__global__ void transpose_w(const float* __restrict__ W0,
                            const float* __restrict__ W1,
                            const float* __restrict__ W2,
                            float* __restrict__ ws) {
    int e = blockIdx.x * 256 + threadIdx.x;
    if (e < WT0_SZ) {
        int d = e / (INF*HH); int r = e % (INF*HH);
        int i = r / HH; int h = r % HH;
        ws[WT0_OFF + e] = W0[(d*HH + h)*INF + i];
    } else if (e < WT0_SZ + WT1_SZ) {
        int e1 = e - WT0_SZ;
        int d = e1 / (HH*HH); int r = e1 % (HH*HH);
        int hin = r / HH; int k = r % HH;
        ws[WT1_OFF + e1] = W1[(d*HH + k)*HH + hin];
    } else if (e < WT0_SZ + WT1_SZ + WT2_SZ) {
        int e2 = e - WT0_SZ - WT1_SZ;
        int d = e2 / (HH*HH); int r = e2 % (HH*HH);
        int hin = r / HH; int k = r % HH;
        ws[WT2_OFF + e2] = W2[(d*HH + k)*HH + hin];
    }
}

__global__ __launch_bounds__(BLK) void mlp_fused(
    const float* __restrict__ x,
    const float* __restrict__ bias0,
    const float* __restrict__ bias1,
    const float* __restrict__ bias2,
    const float* __restrict__ Wout,
    const float* __restrict__ boutp,
    const float* __restrict__ ws,
    float* __restrict__ red_out,
    float* __restrict__ out)
{
    __shared__ float buf[HH][BLK];   // per-thread activation column (64 KB)
    const int tid   = threadIdx.x;
    const int chunk = blockIdx.x;    // window chunk
    const int d     = blockIdx.y;    // output dim
    const int n     = chunk*BLK + tid;
    const bool active = (n < NTOT);
    const int nc = active ? n : (NTOT-1);
    const int b  = nc / NWIN;
    const int tt = nc - b*NWIN;
    const float* xp = x + (size_t)(b*SEQT + tt)*DDIM;

    // stage input column: 32 prev-step features + current-step feature d
    const float4* xp4 = (const float4*)xp;   // 64B-aligned (offset multiple of 16 floats)
    #pragma unroll
    for (int i = 0; i < 8; ++i) {
        float4 v = xp4[i];
        buf[4*i+0][tid] = v.x;
        buf[4*i+1][tid] = v.y;
        buf[4*i+2][tid] = v.z;
        buf[4*i+3][tid] = v.w;
    }
    buf[32][tid] = xp[32 + d];

    const float* Wt0 = ws + WT0_OFF + d*(INF*HH);
    const float* Wt1 = ws + WT1_OFF + d*(HH*HH);
    const float* Wt2 = ws + WT2_OFF + d*(HH*HH);

    float acc[HH];
    unsigned m1lo=0u, m1hi=0u, m2lo=0u, m2hi=0u, m3lo=0u, m3hi=0u;

    // ---------------- layer 1 (33 -> 64) ----------------
    #pragma unroll
    for (int j=0;j<HH;j++) acc[j] = bias0[d*HH + j];
    #pragma unroll 3
    for (int i=0;i<INF;i++){
        float v = buf[i][tid];
        const float* wr = Wt0 + i*HH;     // uniform -> s_load
        #pragma unroll
        for (int j=0;j<HH;j++) acc[j] = fmaf(wr[j], v, acc[j]);
    }
    #pragma unroll
    for (int j=0;j<HH;j++){
        bool pos = acc[j] >= 0.0f;
        if (pos){ if (j<32) m1lo |= (1u<<j); else m1hi |= (1u<<(j-32)); }
        buf[j][tid] = pos ? acc[j] : SLOPE*acc[j];
    }
    // ---------------- layer 2 (64 -> 64) ----------------
    #pragma unroll
    for (int j=0;j<HH;j++) acc[j] = bias1[d*HH + j];
    #pragma unroll 2
    for (int i=0;i<HH;i++){
        float v = buf[i][tid];
        const float* wr = Wt1 + i*HH;
        #pragma unroll
        for (int j=0;j<HH;j++) acc[j] = fmaf(wr[j], v, acc[j]);
    }
    #pragma unroll
    for (int j=0;j<HH;j++){
        bool pos = acc[j] >= 0.0f;
        if (pos){ if (j<32) m2lo |= (1u<<j); else m2hi |= (1u<<(j-32)); }
        buf[j][tid] = pos ? acc[j] : SLOPE*acc[j];
    }
    // ---------------- layer 3 (64 -> 64) ----------------
    #pragma unroll
    for (int j=0;j<HH;j++) acc[j] = bias2[d*HH + j];
    #pragma unroll 2
    for (int i=0;i<HH;i++){
        float v = buf[i][tid];
        const float* wr = Wt2 + i*HH;
        #pragma unroll
        for (int j=0;j<HH;j++) acc[j] = fmaf(wr[j], v, acc[j]);
    }
    #pragma unroll
    for (int j=0;j<HH;j++){
        bool pos = acc[j] >= 0.0f;
        if (pos){ if (j<32) m3lo |= (1u<<j); else m3hi |= (1u<<(j-32)); }
        acc[j] = pos ? acc[j] : SLOPE*acc[j];   // h3 stays in regs
    }
    // ---------------- output head ----------------
    float res = boutp[d];
    #pragma unroll
    for (int j=0;j<HH;j++) res = fmaf(Wout[d*HH + j], acc[j], res);
    if (active) out[(size_t)nc*DDIM + d] = res;

    // ---------------- tangent (JVP wrt input feature 32) ----------------
    // t1 = m1 .* W0[:,32]
    const float* wcol = Wt0 + 32*HH;
    #pragma unroll
    for (int j=0;j<HH;j++){
        unsigned bit = (j<32) ? ((m1lo>>j)&1u) : ((m1hi>>(j-32))&1u);
        float w = wcol[j];
        buf[j][tid] = bit ? w : SLOPE*w;
    }
    // t2 = m2 .* (W1 t1)
    #pragma unroll
    for (int j=0;j<HH;j++) acc[j] = 0.0f;
    #pragma unroll 2
    for (int i=0;i<HH;i++){
        float v = buf[i][tid];
        const float* wr = Wt1 + i*HH;
        #pragma unroll
        for (int j=0;j<HH;j++) acc[j] = fmaf(wr[j], v, acc[j]);
    }
    #pragma unroll
    for (int j=0;j<HH;j++){
        unsigned bit = (j<32) ? ((m2lo>>j)&1u) : ((m2hi>>(j-32))&1u);
        buf[j][tid] = bit ? acc[j] : SLOPE*acc[j];
    }
    // t3 = m3 .* (W2 t2)
    #pragma unroll
    for (int j=0;j<HH;j++) acc[j] = 0.0f;
    #pragma unroll 2
    for (int i=0;i<HH;i++){
        float v = buf[i][tid];
        const float* wr = Wt2 + i*HH;
        #pragma unroll
        for (int j=0;j<HH;j++) acc[j] = fmaf(wr[j], v, acc[j]);
    }
    float dres = 0.0f;
    #pragma unroll
    for (int j=0;j<HH;j++){
        unsigned bit = (j<32) ? ((m3lo>>j)&1u) : ((m3hi>>(j-32))&1u);
        float tv = bit ? acc[j] : SLOPE*acc[j];
        dres = fmaf(Wout[d*HH + j], tv, dres);
    }
    float logabs = active ? logf(fabsf(dres)) : 0.0f;

    // ---------------- deterministic block reduction, split by batch b ----------------
    __syncthreads();
    float* red = &buf[0][0];
    const int cb0 = (chunk*BLK)/NWIN;   // first batch index in this chunk
    red[tid] = (active && b==cb0) ? logabs : 0.0f;
    __syncthreads();
    for (int s=BLK/2; s>0; s>>=1){
        if (tid < s) red[tid] += red[tid+s];
        __syncthreads();
    }
    float s0 = red[0];
    __syncthreads();
    red[tid] = (active && b==(cb0+1)) ? logabs : 0.0f;
    __syncthreads();
    for (int s=BLK/2; s>0; s>>=1){
        if (tid < s) red[tid] += red[tid+s];
        __syncthreads();
    }
    if (tid == 0){
        red_out[(d*NCHUNK + chunk)*2 + 0] = s0;
        red_out[(d*NCHUNK + chunk)*2 + 1] = red[0];
    }
}

// Deterministic final reduction: 32 threads, fixed iteration order.
__global__ void final_red(const float* __restrict__ red, float* __restrict__ out_sld) {
    int b = threadIdx.x;
    if (b >= NB) return;
    float s = 0.0f;
    for (int d=0; d<DDIM; ++d){
        for (int c=0; c<NCHUNK; ++c){
            int cb0 = (c*BLK)/NWIN;
            const float* r = red + (d*NCHUNK + c)*2;
            if (cb0   == b) s += r[0];
            if (cb0+1 == b) s += r[1];
        }
    }
    out_sld[b] = s;
}

extern "C" void kernel_launch(void* const* d_in, const int* in_sizes, int n_in,
                              void* d_out, int out_size, void* d_ws, size_t ws_size,
                              hipStream_t stream) {
    const float* x    = (const float*)d_in[0];
    const float* W0   = (const float*)d_in[1];
    const float* b0   = (const float*)d_in[2];
    const float* W1   = (const float*)d_in[3];
    const float* b1   = (const float*)d_in[4];
    const float* W2   = (const float*)d_in[5];
    const float* b2   = (const float*)d_in[6];
    const float* Wout = (const float*)d_in[7];
    const float* bout = (const float*)d_in[8];
    float* out = (float*)d_out;
    float* ws  = (float*)d_ws;

    transpose_w<<<(WT0_SZ+WT1_SZ+WT2_SZ+255)/256, 256, 0, stream>>>(W0, W1, W2, ws);

    dim3 grid(NCHUNK, DDIM);
    mlp_fused<<<grid, BLK, 0, stream>>>(x, b0, b1, b2, Wout, bout,
                                        ws, ws + RED_OFF, out);

    final_red<<<1, 32, 0, stream>>>(ws + RED_OFF, out + (size_t)NTOT*DDIM);
}

// Round 2
// 162.146 us; speedup vs baseline: 2.3324x; 2.3324x over previous
//
#include <hip/hip_runtime.h>
#include <math.h>

#define NB 32
#define SEQT 512
#define DDIM 16
#define NWIN 510
#define NTOT (NB*NWIN)      // 16320
#define HH 64
#define SLOPE 0.2f
#define NR 64               // windows per block
#define NCH (NTOT/NR)       // 255 (exact)

typedef __attribute__((ext_vector_type(8))) short sh8;   // 8 bf16 = 4 VGPR
typedef __attribute__((ext_vector_type(4))) float f4;

// ws byte offsets
#define W0B_OFF 0            // bf16 [16][64][64]  (cols 33..63 zero)
#define W1B_OFF 131072       // bf16 [16][64][64]
#define W2B_OFF 262144       // bf16 [16][64][64]
#define WCOL_OFF 393216      // f32  [16][64]  = W0[d][h][32]
#define RED_OFF 397312       // f32  [255][16][2]

__device__ inline unsigned short f2bf(float f){
    unsigned u = __float_as_uint(f);
    unsigned r = (u + 0x7FFFu + ((u>>16)&1u)) >> 16;   // RNE
    return (unsigned short)r;
}

__global__ void prep(const float* __restrict__ W0, const float* __restrict__ W1,
                     const float* __restrict__ W2, unsigned char* __restrict__ wsb){
    int e = blockIdx.x*256 + threadIdx.x;
    if (e < 65536){
        unsigned short* W0b = (unsigned short*)(wsb + W0B_OFF);
        int d = e >> 12, r = e & 4095, h = r >> 6, kk = r & 63;
        float v = (kk < 33) ? W0[(d*64 + h)*33 + kk] : 0.f;
        W0b[e] = f2bf(v);
    } else if (e < 131072){
        unsigned short* W1b = (unsigned short*)(wsb + W1B_OFF);
        int i = e - 65536;
        W1b[i] = f2bf(W1[i]);           // [d][k][h] already A-layout
    } else if (e < 196608){
        unsigned short* W2b = (unsigned short*)(wsb + W2B_OFF);
        int i = e - 131072;
        W2b[i] = f2bf(W2[i]);
    } else if (e < 197632){
        int i = e - 196608;
        int d = i >> 6, h = i & 63;
        ((float*)(wsb + WCOL_OFF))[i] = W0[(d*64 + h)*33 + 32];
    }
}

// B fragment: lane reads LDS row (16w+nl), 16B at col (32*ks + 8*hi), XOR-swizzled.
// A fragment: lane = m (nl), k-group hi: 16B of weight row (16t+nl) at col.
__device__ inline void layer_gemm(const unsigned char* src, const unsigned char* wA,
                                  int w, int nl, int hi, f4 acc[4]){
    #pragma unroll
    for (int ks = 0; ks < 2; ++ks){
        int col = 32*ks + 8*hi;
        sh8 bfrag = *(const sh8*)&src[(16*w + nl)*128 + ((2*col) ^ ((nl&7)<<4))];
        #pragma unroll
        for (int t = 0; t < 4; ++t){
            sh8 afrag = *(const sh8*)&wA[((16*t + nl)*64 + col)*2];
            acc[t] = __builtin_amdgcn_mfma_f32_16x16x32_bf16(afrag, bfrag, acc[t], 0,0,0);
        }
    }
}

// leaky-relu, record mask (bit t*4+r), store bf16 to dst[n][h] swizzled; acc <- activated
__device__ inline void act_store(unsigned char* dst, int w, int nl, int hi,
                                 f4 acc[4], unsigned* mask){
    unsigned m = 0;
    #pragma unroll
    for (int t = 0; t < 4; ++t){
        float v[4];
        #pragma unroll
        for (int r = 0; r < 4; ++r){
            float a = acc[t][r];
            bool pos = a >= 0.f;
            if (pos) m |= 1u << (t*4 + r);
            v[r] = pos ? a : SLOPE*a;
            acc[t][r] = v[r];
        }
        uint2 pk;
        pk.x = (unsigned)f2bf(v[0]) | ((unsigned)f2bf(v[1]) << 16);
        pk.y = (unsigned)f2bf(v[2]) | ((unsigned)f2bf(v[3]) << 16);
        *(uint2*)&dst[(16*w + nl)*128 + ((32*t + 8*hi) ^ ((nl&7)<<4))] = pk;
    }
    *mask = m;
}

// tangent epilogue: apply stored mask, store bf16; acc <- masked value
__device__ inline void tan_store(unsigned char* dst, int w, int nl, int hi,
                                 f4 acc[4], unsigned mask){
    #pragma unroll
    for (int t = 0; t < 4; ++t){
        float v[4];
        #pragma unroll
        for (int r = 0; r < 4; ++r){
            float a = acc[t][r];
            v[r] = ((mask >> (t*4 + r)) & 1u) ? a : SLOPE*a;
            acc[t][r] = v[r];
        }
        uint2 pk;
        pk.x = (unsigned)f2bf(v[0]) | ((unsigned)f2bf(v[1]) << 16);
        pk.y = (unsigned)f2bf(v[2]) | ((unsigned)f2bf(v[3]) << 16);
        *(uint2*)&dst[(16*w + nl)*128 + ((32*t + 8*hi) ^ ((nl&7)<<4))] = pk;
    }
}

__global__ __launch_bounds__(256, 4) void mlp(
    const float* __restrict__ x,
    const float* __restrict__ bias0, const float* __restrict__ bias1,
    const float* __restrict__ bias2,
    const float* __restrict__ Wout, const float* __restrict__ boutp,
    const unsigned char* __restrict__ wsb,
    float* __restrict__ red, float* __restrict__ out)
{
    __shared__ __align__(16) unsigned char lds[3][NR*128];  // 24 KB
    __shared__ float wred[4][2];

    const int tid  = threadIdx.x;
    const int lane = tid & 63;
    const int w    = tid >> 6;        // wave id = n-tile
    const int nl   = lane & 15;
    const int hi   = lane >> 4;
    const int chunk = blockIdx.x;
    const int d     = blockIdx.y;

    // ---------------- stage input: In[n][0..32]=yy|xx, rest zero ----------------
    {
        int row = tid >> 2, q = tid & 3;
        int n = chunk*NR + row;
        int b = n / NWIN, tn = n - b*NWIN;
        const float* xp = x + (size_t)(b*SEQT + tn)*DDIM + 8*q;
        float4 v0 = ((const float4*)xp)[0];
        float4 v1 = ((const float4*)xp)[1];
        sh8 s;
        s[0]=(short)f2bf(v0.x); s[1]=(short)f2bf(v0.y); s[2]=(short)f2bf(v0.z); s[3]=(short)f2bf(v0.w);
        s[4]=(short)f2bf(v1.x); s[5]=(short)f2bf(v1.y); s[6]=(short)f2bf(v1.z); s[7]=(short)f2bf(v1.w);
        *(sh8*)&lds[0][row*128 + ((16*q) ^ ((row&7)<<4))] = s;
        if (tid < NR){
            int rr = tid;
            int n2 = chunk*NR + rr;
            int bb = n2 / NWIN, t2 = n2 - bb*NWIN;
            float xx = x[(size_t)(bb*SEQT + t2 + 2)*DDIM + d];
            sh8 z = {0,0,0,0,0,0,0,0};
            sh8 sx = z; sx[0] = (short)f2bf(xx);
            int rs = (rr&7)<<4;
            *(sh8*)&lds[0][rr*128 + (64  ^ rs)] = sx;  // cols 32..39
            *(sh8*)&lds[0][rr*128 + (80  ^ rs)] = z;   // 40..47
            *(sh8*)&lds[0][rr*128 + (96  ^ rs)] = z;   // 48..55
            *(sh8*)&lds[0][rr*128 + (112 ^ rs)] = z;   // 56..63
        }
    }
    __syncthreads();

    const unsigned char* W0b = wsb + W0B_OFF + d*8192;
    const unsigned char* W1b = wsb + W1B_OFF + d*8192;
    const unsigned char* W2b = wsb + W2B_OFF + d*8192;

    f4 acc[4];
    unsigned mask1, mask2, mask3;

    // ---------------- L1 ----------------
    #pragma unroll
    for (int t = 0; t < 4; ++t){
        float4 bv = *(const float4*)(bias0 + d*64 + 16*t + 4*hi);
        acc[t][0]=bv.x; acc[t][1]=bv.y; acc[t][2]=bv.z; acc[t][3]=bv.w;
    }
    layer_gemm(lds[0], W0b, w, nl, hi, acc);
    act_store(lds[1], w, nl, hi, acc, &mask1);
    __syncthreads();

    // ---------------- L2 ----------------
    #pragma unroll
    for (int t = 0; t < 4; ++t){
        float4 bv = *(const float4*)(bias1 + d*64 + 16*t + 4*hi);
        acc[t][0]=bv.x; acc[t][1]=bv.y; acc[t][2]=bv.z; acc[t][3]=bv.w;
    }
    layer_gemm(lds[1], W1b, w, nl, hi, acc);
    act_store(lds[2], w, nl, hi, acc, &mask2);
    __syncthreads();

    // ---------------- L3 (activations stay in regs) ----------------
    #pragma unroll
    for (int t = 0; t < 4; ++t){
        float4 bv = *(const float4*)(bias2 + d*64 + 16*t + 4*hi);
        acc[t][0]=bv.x; acc[t][1]=bv.y; acc[t][2]=bv.z; acc[t][3]=bv.w;
    }
    layer_gemm(lds[2], W2b, w, nl, hi, acc);
    mask3 = 0;
    #pragma unroll
    for (int t = 0; t < 4; ++t)
        #pragma unroll
        for (int r = 0; r < 4; ++r){
            float a = acc[t][r];
            bool pos = a >= 0.f;
            if (pos) mask3 |= 1u << (t*4 + r);
            acc[t][r] = pos ? a : SLOPE*a;
        }

    // ---------------- output head ----------------
    float wout_l[4][4];
    float res = 0.f;
    #pragma unroll
    for (int t = 0; t < 4; ++t){
        float4 wv = *(const float4*)(Wout + d*64 + 16*t + 4*hi);
        wout_l[t][0]=wv.x; wout_l[t][1]=wv.y; wout_l[t][2]=wv.z; wout_l[t][3]=wv.w;
        #pragma unroll
        for (int r = 0; r < 4; ++r) res = fmaf(wout_l[t][r], acc[t][r], res);
    }
    res += __shfl_xor(res, 16);
    res += __shfl_xor(res, 32);
    res += boutp[d];
    if (hi == 0)
        out[(size_t)(chunk*NR + 16*w + nl)*DDIM + d] = res;

    // ---------------- tangent: T1 = mask1 .* w0col  (into buffer 0) ----------------
    {
        const float* wcol = (const float*)(wsb + WCOL_OFF) + d*64;
        #pragma unroll
        for (int t = 0; t < 4; ++t){
            float4 wv = *(const float4*)(wcol + 16*t + 4*hi);
            float v[4] = {wv.x, wv.y, wv.z, wv.w};
            #pragma unroll
            for (int r = 0; r < 4; ++r)
                if (!((mask1 >> (t*4 + r)) & 1u)) v[r] *= SLOPE;
            uint2 pk;
            pk.x = (unsigned)f2bf(v[0]) | ((unsigned)f2bf(v[1]) << 16);
            pk.y = (unsigned)f2bf(v[2]) | ((unsigned)f2bf(v[3]) << 16);
            *(uint2*)&lds[0][(16*w + nl)*128 + ((32*t + 8*hi) ^ ((nl&7)<<4))] = pk;
        }
    }
    __syncthreads();

    // ---------------- T2 = mask2 .* (W1 T1)  (into buffer 1) ----------------
    #pragma unroll
    for (int t = 0; t < 4; ++t) acc[t] = (f4){0.f,0.f,0.f,0.f};
    layer_gemm(lds[0], W1b, w, nl, hi, acc);
    tan_store(lds[1], w, nl, hi, acc, mask2);
    __syncthreads();

    // ---------------- T3 = mask3 .* (W2 T2) ; dres ----------------
    #pragma unroll
    for (int t = 0; t < 4; ++t) acc[t] = (f4){0.f,0.f,0.f,0.f};
    layer_gemm(lds[1], W2b, w, nl, hi, acc);
    float dres = 0.f;
    #pragma unroll
    for (int t = 0; t < 4; ++t)
        #pragma unroll
        for (int r = 0; r < 4; ++r){
            float a = acc[t][r];
            float v = ((mask3 >> (t*4 + r)) & 1u) ? a : SLOPE*a;
            dres = fmaf(wout_l[t][r], v, dres);
        }
    dres += __shfl_xor(dres, 16);
    dres += __shfl_xor(dres, 32);
    float logabs = logf(fabsf(dres));

    // ---------------- deterministic reduction (split by batch) ----------------
    {
        int n   = chunk*NR + 16*w + nl;
        int b   = n / NWIN;
        int cb0 = (chunk*NR) / NWIN;
        float v0 = (b == cb0)     ? logabs : 0.f;
        float v1 = (b == cb0 + 1) ? logabs : 0.f;
        #pragma unroll
        for (int s = 1; s < 16; s <<= 1){
            v0 += __shfl_xor(v0, s);
            v1 += __shfl_xor(v1, s);
        }
        if (lane == 0){ wred[w][0] = v0 * 0.25f; wred[w][1] = v1 * 0.25f; }
        // (hi-groups hold identical copies; xor-tree over 16 lanes also folds the
        //  4 copies? no — masks 1,2,4,8 stay within 16-lane groups, copies are
        //  per-group identical, lane0 of wave has the correct single-group sum.)
    }
    __syncthreads();
    if (tid == 0){
        float s0 = wred[0][0] + wred[1][0] + wred[2][0] + wred[3][0];
        float s1 = wred[0][1] + wred[1][1] + wred[2][1] + wred[3][1];
        red[(chunk*16 + d)*2 + 0] = s0 * 4.f;
        red[(chunk*16 + d)*2 + 1] = s1 * 4.f;
    }
}

__global__ void final_red(const float* __restrict__ red, float* __restrict__ sld){
    __shared__ float pp[DDIM][NB];
    int t = threadIdx.x;              // 512 threads: (d, b)
    int b = t & 31, d = t >> 5;
    float s = 0.f;
    for (int c = 0; c < NCH; ++c){
        int cb0 = (c*NR)/NWIN;
        float r0 = red[(c*16 + d)*2 + 0];
        float r1 = red[(c*16 + d)*2 + 1];
        if (cb0     == b) s += r0;
        if (cb0 + 1 == b) s += r1;
    }
    pp[d][b] = s;
    __syncthreads();
    if (t < NB){
        float a = 0.f;
        #pragma unroll
        for (int dd = 0; dd < DDIM; ++dd) a += pp[dd][t];
        sld[t] = a;
    }
}

extern "C" void kernel_launch(void* const* d_in, const int* in_sizes, int n_in,
                              void* d_out, int out_size, void* d_ws, size_t ws_size,
                              hipStream_t stream) {
    const float* x    = (const float*)d_in[0];
    const float* W0   = (const float*)d_in[1];
    const float* b0   = (const float*)d_in[2];
    const float* W1   = (const float*)d_in[3];
    const float* b1   = (const float*)d_in[4];
    const float* W2   = (const float*)d_in[5];
    const float* b2   = (const float*)d_in[6];
    const float* Wout = (const float*)d_in[7];
    const float* bout = (const float*)d_in[8];
    float* out = (float*)d_out;
    unsigned char* wsb = (unsigned char*)d_ws;

    prep<<<(197632 + 255)/256, 256, 0, stream>>>(W0, W1, W2, wsb);

    dim3 grid(NCH, DDIM);
    mlp<<<grid, 256, 0, stream>>>(x, b0, b1, b2, Wout, bout, wsb,
                                  (float*)(wsb + RED_OFF), out);

    final_red<<<1, 512, 0, stream>>>((const float*)(wsb + RED_OFF),
                                     out + (size_t)NTOT*DDIM);
}

// Round 3
// 64.294 us; speedup vs baseline: 5.8821x; 2.5219x over previous
//
#include <hip/hip_runtime.h>
#include <hip/hip_bf16.h>
#include <math.h>

#define NB 32
#define SEQT 512
#define DDIM 16
#define NWIN 510
#define NTOT (NB*NWIN)      // 16320
#define SLOPE 0.2f
#define NR 64               // windows per block
#define NCH (NTOT/NR)       // 255 (exact)

typedef __attribute__((ext_vector_type(8))) short sh8;   // 8 bf16
typedef __attribute__((ext_vector_type(4))) float f4;

// ws byte offsets
#define W0B_OFF 0            // bf16 [16][64][32]   (k = 0..31 only)
#define W1B_OFF 65536        // bf16 [16][64][64]
#define W2B_OFF 196608       // bf16 [16][64][64]
#define WCOL_OFF 327680      // f32  [16][64]  = W0[d][h][32]
#define RED_OFF 331776       // f32  [255*4][16][2]
#define NPREP 164864

static __device__ __forceinline__ unsigned short bfb(float f){
    union { __hip_bfloat16 h; unsigned short u; } cv;
    cv.h = __float2bfloat16(f);
    return cv.u;
}
static __device__ __forceinline__ unsigned pk2(float a, float b){
    return (unsigned)bfb(a) | ((unsigned)bfb(b) << 16);
}

__global__ void prep(const float* __restrict__ W0, const float* __restrict__ W1,
                     const float* __restrict__ W2, unsigned char* __restrict__ wsb){
    int e = blockIdx.x*256 + threadIdx.x;
    if (e < 32768){
        unsigned short* W0b = (unsigned short*)(wsb + W0B_OFF);
        int d = e >> 11, r = e & 2047, h = r >> 5, k = r & 31;
        W0b[e] = bfb(W0[(d*64 + h)*33 + k]);
    } else if (e < 98304){
        ((unsigned short*)(wsb + W1B_OFF))[e - 32768] = bfb(W1[e - 32768]);
    } else if (e < 163840){
        ((unsigned short*)(wsb + W2B_OFF))[e - 98304] = bfb(W2[e - 98304]);
    } else if (e < NPREP){
        int i = e - 163840;
        int d = i >> 6, h = i & 63;
        ((float*)(wsb + WCOL_OFF))[i] = W0[(d*64 + h)*33 + 32];
    }
}

// one 64-wide-K GEMM step: B rows from LDS (swizzled), A rows from global bf16 [64][64]
static __device__ __forceinline__ void gemm64(const unsigned char* src,
                                              const unsigned char* __restrict__ wA,
                                              int row, int nl, int hi, f4 acc[4]){
    #pragma unroll
    for (int ks = 0; ks < 2; ++ks){
        int col = 32*ks + 8*hi;
        sh8 bfrag = *(const sh8*)&src[row*128 + ((2*col) ^ ((nl&7)<<4))];
        #pragma unroll
        for (int t = 0; t < 4; ++t){
            sh8 afrag = *(const sh8*)&wA[((16*t+nl)*64 + col)*2];
            acc[t] = __builtin_amdgcn_mfma_f32_16x16x32_bf16(afrag, bfrag, acc[t], 0,0,0);
        }
    }
}

// leaky-relu epilogue: record NEG mask, activate, store bf16 swizzled
static __device__ __forceinline__ void ep_store(unsigned char* dst, int row, int nl, int hi,
                                                f4 acc[4], unsigned* maskNeg){
    unsigned m = 0;
    #pragma unroll
    for (int t=0;t<4;++t){
        float v[4];
        #pragma unroll
        for (int r=0;r<4;++r){
            float a = acc[t][r];
            m |= (__float_as_uint(a) >> 31) << (t*4+r);
            v[r] = fmaxf(a, SLOPE*a);
        }
        uint2 pk; pk.x = pk2(v[0],v[1]); pk.y = pk2(v[2],v[3]);
        *(uint2*)&dst[row*128 + ((32*t + 8*hi) ^ ((nl&7)<<4))] = pk;
    }
    *maskNeg = m;
}

// tangent epilogue: apply NEG mask, store bf16 swizzled
static __device__ __forceinline__ void tan_store2(unsigned char* dst, int row, int nl, int hi,
                                                  f4 acc[4], unsigned maskNeg){
    #pragma unroll
    for (int t=0;t<4;++t){
        float v[4];
        #pragma unroll
        for (int r=0;r<4;++r){
            float a = acc[t][r];
            v[r] = ((maskNeg >> (t*4+r)) & 1u) ? SLOPE*a : a;
        }
        uint2 pk; pk.x = pk2(v[0],v[1]); pk.y = pk2(v[2],v[3]);
        *(uint2*)&dst[row*128 + ((32*t + 8*hi) ^ ((nl&7)<<4))] = pk;
    }
}

__global__ __launch_bounds__(256, 4) void mlp(
    const float* __restrict__ x,
    const float* __restrict__ bias0, const float* __restrict__ bias1,
    const float* __restrict__ bias2,
    const float* __restrict__ Wout, const float* __restrict__ boutp,
    const unsigned char* __restrict__ wsb,
    float* __restrict__ red, float* __restrict__ out)
{
    // no __syncthreads anywhere: every wave touches only rows [16w, 16w+16)
    __shared__ __align__(16) unsigned char bufC[NR*64];    // input, 64B rows (K=32)
    __shared__ __align__(16) unsigned char bufA[NR*128];   // h1 -> h2 (in-place)
    __shared__ __align__(16) unsigned char bufB[NR*128];   // t1 -> t2 (in-place)

    const int tid  = threadIdx.x;
    const int lane = tid & 63;
    const int w    = tid >> 6;
    const int nl   = lane & 15;
    const int hi   = lane >> 4;
    const int row  = 16*w + nl;
    const int chunk = blockIdx.x;
    const int d     = blockIdx.y;

    // ---- stage input (wave-private rows): cols 0..31 = yy ----
    {
        int rowg = 16*w + (lane>>2);
        int q = lane & 3;
        int ns = chunk*NR + rowg;
        int bs = ns / NWIN, ts = ns - bs*NWIN;
        const float* gp = x + (size_t)(bs*SEQT + ts)*DDIM + 8*q;
        float4 v0 = ((const float4*)gp)[0];
        float4 v1 = ((const float4*)gp)[1];
        uint4 pk;
        pk.x = pk2(v0.x, v0.y); pk.y = pk2(v0.z, v0.w);
        pk.z = pk2(v1.x, v1.y); pk.w = pk2(v1.z, v1.w);
        *(uint4*)&bufC[rowg*64 + 16*(q ^ (rowg & 3))] = pk;
    }

    // per-lane window & current-step feature
    const int n = chunk*NR + row;
    const int b = n / NWIN, tn = n - b*NWIN;
    const float xx = x[(size_t)(b*SEQT + tn + 2)*DDIM + d];

    const unsigned char* W0b = wsb + W0B_OFF + d*4096;
    const unsigned char* W1b = wsb + W1B_OFF + d*8192;
    const unsigned char* W2b = wsb + W2B_OFF + d*8192;
    const float* wcolp = (const float*)(wsb + WCOL_OFF) + d*64;

    float wcol[4][4], wout_l[4][4];
    #pragma unroll
    for (int t=0;t<4;++t){
        float4 wv = *(const float4*)(wcolp + 16*t + 4*hi);
        wcol[t][0]=wv.x; wcol[t][1]=wv.y; wcol[t][2]=wv.z; wcol[t][3]=wv.w;
        float4 ov = *(const float4*)(Wout + d*64 + 16*t + 4*hi);
        wout_l[t][0]=ov.x; wout_l[t][1]=ov.y; wout_l[t][2]=ov.z; wout_l[t][3]=ov.w;
    }

    f4 accA[4], accB[4];
    unsigned mask1, mask2, mask3;

    // ---------------- L1 (K=32 MFMA + fp32 rank-1 for col 32) ----------------
    #pragma unroll
    for (int t=0;t<4;++t){
        float4 bv = *(const float4*)(bias0 + d*64 + 16*t + 4*hi);
        accA[t][0]=bv.x; accA[t][1]=bv.y; accA[t][2]=bv.z; accA[t][3]=bv.w;
    }
    {
        sh8 bfrag = *(const sh8*)&bufC[row*64 + 16*(hi ^ (nl & 3))];
        #pragma unroll
        for (int t=0;t<4;++t){
            sh8 afrag = *(const sh8*)&W0b[((16*t+nl)*32 + 8*hi)*2];
            accA[t] = __builtin_amdgcn_mfma_f32_16x16x32_bf16(afrag, bfrag, accA[t], 0,0,0);
        }
    }
    // epilogue: rank-1, mask1, act -> bufA ; t1 = deriv1.*wcol -> bufB
    mask1 = 0;
    #pragma unroll
    for (int t=0;t<4;++t){
        float v[4], tv[4];
        #pragma unroll
        for (int r=0;r<4;++r){
            float a = fmaf(wcol[t][r], xx, accA[t][r]);
            unsigned neg = __float_as_uint(a) >> 31;
            mask1 |= neg << (t*4+r);
            v[r]  = fmaxf(a, SLOPE*a);
            tv[r] = neg ? SLOPE*wcol[t][r] : wcol[t][r];
        }
        uint2 ph; ph.x = pk2(v[0],v[1]);  ph.y = pk2(v[2],v[3]);
        *(uint2*)&bufA[row*128 + ((32*t + 8*hi) ^ ((nl&7)<<4))] = ph;
        uint2 pt; pt.x = pk2(tv[0],tv[1]); pt.y = pk2(tv[2],tv[3]);
        *(uint2*)&bufB[row*128 + ((32*t + 8*hi) ^ ((nl&7)<<4))] = pt;
    }

    // ---------------- L2: h2 = act(W1 h1 + b1)  (bufA in-place) ----------------
    #pragma unroll
    for (int t=0;t<4;++t){
        float4 bv = *(const float4*)(bias1 + d*64 + 16*t + 4*hi);
        accA[t][0]=bv.x; accA[t][1]=bv.y; accA[t][2]=bv.z; accA[t][3]=bv.w;
    }
    gemm64(bufA, W1b, row, nl, hi, accA);
    ep_store(bufA, row, nl, hi, accA, &mask2);

    // ---------------- T2: t2 = d2 .* (W1 t1)  (bufB in-place) ----------------
    #pragma unroll
    for (int t=0;t<4;++t) accB[t] = (f4){0.f,0.f,0.f,0.f};
    gemm64(bufB, W1b, row, nl, hi, accB);
    tan_store2(bufB, row, nl, hi, accB, mask2);

    // ---------------- L3: h3 = act(W2 h2 + b2)  (stays in regs) ----------------
    #pragma unroll
    for (int t=0;t<4;++t){
        float4 bv = *(const float4*)(bias2 + d*64 + 16*t + 4*hi);
        accA[t][0]=bv.x; accA[t][1]=bv.y; accA[t][2]=bv.z; accA[t][3]=bv.w;
    }
    gemm64(bufA, W2b, row, nl, hi, accA);
    mask3 = 0;
    #pragma unroll
    for (int t=0;t<4;++t)
        #pragma unroll
        for (int r=0;r<4;++r){
            float a = accA[t][r];
            mask3 |= (__float_as_uint(a) >> 31) << (t*4+r);
            accA[t][r] = fmaxf(a, SLOPE*a);
        }

    // ---------------- T3: t3 = d3 .* (W2 t2)  (regs) ----------------
    #pragma unroll
    for (int t=0;t<4;++t) accB[t] = (f4){0.f,0.f,0.f,0.f};
    gemm64(bufB, W2b, row, nl, hi, accB);

    // ---------------- head + logdet ----------------
    float res = 0.f, dres = 0.f;
    #pragma unroll
    for (int t=0;t<4;++t)
        #pragma unroll
        for (int r=0;r<4;++r){
            res = fmaf(wout_l[t][r], accA[t][r], res);
            float a = accB[t][r];
            float tv = ((mask3 >> (t*4+r)) & 1u) ? SLOPE*a : a;
            dres = fmaf(wout_l[t][r], tv, dres);
        }
    res  += __shfl_xor(res, 16);  res  += __shfl_xor(res, 32);
    dres += __shfl_xor(dres, 16); dres += __shfl_xor(dres, 32);
    res += boutp[d];
    if (hi == 0)
        out[(size_t)n*DDIM + d] = res;

    float logabs = __logf(fabsf(dres));

    // ---------------- per-wave deterministic reduction (split by batch) ----------------
    {
        int cb0 = (chunk*NR) / NWIN;
        float v0 = (b == cb0)     ? logabs : 0.f;
        float v1 = (b == cb0 + 1) ? logabs : 0.f;
        #pragma unroll
        for (int s = 1; s < 16; s <<= 1){
            v0 += __shfl_xor(v0, s);
            v1 += __shfl_xor(v1, s);
        }
        if (lane == 0){
            red[((size_t)(chunk*4 + w)*16 + d)*2 + 0] = v0;
            red[((size_t)(chunk*4 + w)*16 + d)*2 + 1] = v1;
        }
    }
}

__global__ void final_red(const float* __restrict__ red, float* __restrict__ sld){
    __shared__ float pp[DDIM][16];
    const int b = blockIdx.x;
    const int tid = threadIdx.x;
    const int d = tid & 15, j = tid >> 4;   // j = 0..15
    float s = 0.f;
    for (int gw = j; gw < NCH*4; gw += 16){
        int chunk = gw >> 2;
        int cb0 = (chunk*NR)/NWIN;
        const float* r = red + ((size_t)gw*16 + d)*2;
        if (cb0     == b) s += r[0];
        if (cb0 + 1 == b) s += r[1];
    }
    pp[d][j] = s;
    __syncthreads();
    if (tid < DDIM){
        float a = 0.f;
        #pragma unroll
        for (int k=0;k<16;++k) a += pp[tid][k];
        pp[tid][0] = a;
    }
    __syncthreads();
    if (tid == 0){
        float a = 0.f;
        #pragma unroll
        for (int dd=0; dd<DDIM; ++dd) a += pp[dd][0];
        sld[b] = a;
    }
}

extern "C" void kernel_launch(void* const* d_in, const int* in_sizes, int n_in,
                              void* d_out, int out_size, void* d_ws, size_t ws_size,
                              hipStream_t stream) {
    const float* x    = (const float*)d_in[0];
    const float* W0   = (const float*)d_in[1];
    const float* b0   = (const float*)d_in[2];
    const float* W1   = (const float*)d_in[3];
    const float* b1   = (const float*)d_in[4];
    const float* W2   = (const float*)d_in[5];
    const float* b2   = (const float*)d_in[6];
    const float* Wout = (const float*)d_in[7];
    const float* bout = (const float*)d_in[8];
    float* out = (float*)d_out;
    unsigned char* wsb = (unsigned char*)d_ws;

    prep<<<(NPREP + 255)/256, 256, 0, stream>>>(W0, W1, W2, wsb);

    dim3 grid(NCH, DDIM);
    mlp<<<grid, 256, 0, stream>>>(x, b0, b1, b2, Wout, bout, wsb,
                                  (float*)(wsb + RED_OFF), out);

    final_red<<<NB, 256, 0, stream>>>((const float*)(wsb + RED_OFF),
                                      out + (size_t)NTOT*DDIM);
}

// Round 4
// 63.858 us; speedup vs baseline: 5.9222x; 1.0068x over previous
//
#include <hip/hip_runtime.h>
#include <hip/hip_bf16.h>
#include <math.h>

#define NB 32
#define SEQT 512
#define DDIM 16
#define NWIN 510
#define NTOT (NB*NWIN)      // 16320
#define SLOPE 0.2f
#define NR 64               // windows per block
#define NCH (NTOT/NR)       // 255 (exact)

typedef __attribute__((ext_vector_type(8))) short sh8;   // 8 bf16
typedef __attribute__((ext_vector_type(4))) float f4;

// ws byte offsets
#define W0B_OFF 0            // bf16 [16][64][32]   (k = 0..31 only)
#define W1B_OFF 65536        // bf16 [16][64][64]
#define W2B_OFF 196608       // bf16 [16][64][64]
#define WCOL_OFF 327680      // f32  [16][64]  = W0[d][h][32]
#define RED_OFF 331776       // f32  [255*4][16][2]
#define NPREP 164864

static __device__ __forceinline__ unsigned short bfb(float f){
    union { __hip_bfloat16 h; unsigned short u; } cv;
    cv.h = __float2bfloat16(f);
    return cv.u;
}
static __device__ __forceinline__ unsigned pk2(float a, float b){
    return (unsigned)bfb(a) | ((unsigned)bfb(b) << 16);
}

__global__ void prep(const float* __restrict__ W0, const float* __restrict__ W1,
                     const float* __restrict__ W2, unsigned char* __restrict__ wsb){
    int e = blockIdx.x*256 + threadIdx.x;
    if (e < 32768){
        unsigned short* W0b = (unsigned short*)(wsb + W0B_OFF);
        int d = e >> 11, r = e & 2047, h = r >> 5, k = r & 31;
        W0b[e] = bfb(W0[(d*64 + h)*33 + k]);
    } else if (e < 98304){
        ((unsigned short*)(wsb + W1B_OFF))[e - 32768] = bfb(W1[e - 32768]);
    } else if (e < 163840){
        ((unsigned short*)(wsb + W2B_OFF))[e - 98304] = bfb(W2[e - 98304]);
    } else if (e < NPREP){
        int i = e - 163840;
        int d = i >> 6, h = i & 63;
        ((float*)(wsb + WCOL_OFF))[i] = W0[(d*64 + h)*33 + 32];
    }
}

__global__ __launch_bounds__(256, 3) void mlp(
    const float* __restrict__ x,
    const float* __restrict__ bias0, const float* __restrict__ bias1,
    const float* __restrict__ bias2,
    const float* __restrict__ Wout, const float* __restrict__ boutp,
    const unsigned char* __restrict__ wsb,
    float* __restrict__ red, float* __restrict__ out)
{
    // no __syncthreads anywhere: every wave touches only rows [16w, 16w+16)
    __shared__ __align__(16) unsigned char bufC[NR*64];    // input, 64B rows (K=32)
    __shared__ __align__(16) unsigned char bufA[NR*128];   // h1 -> h2 (in-place)
    __shared__ __align__(16) unsigned char bufB[NR*128];   // t1 -> t2 (in-place)

    const int tid  = threadIdx.x;
    const int lane = tid & 63;
    const int w    = tid >> 6;
    const int nl   = lane & 15;
    const int hi   = lane >> 4;
    const int row  = 16*w + nl;
    const int chunk = blockIdx.x;
    const int d     = blockIdx.y;
    const int rsw   = (nl & 7) << 4;      // XOR swizzle for this lane's row

    const unsigned char* W0b = wsb + W0B_OFF + d*4096;
    const unsigned char* W1b = wsb + W1B_OFF + d*8192;
    const unsigned char* W2b = wsb + W2B_OFF + d*8192;

    // ---- preload the twice-used weight fragments into registers ----
    sh8 w1f[2][4], w2f[2][4];
    #pragma unroll
    for (int ks=0; ks<2; ++ks)
        #pragma unroll
        for (int t=0; t<4; ++t){
            int off = ((16*t+nl)*64 + 32*ks + 8*hi)*2;
            w1f[ks][t] = *(const sh8*)&W1b[off];
            w2f[ks][t] = *(const sh8*)&W2b[off];
        }

    // ---- stage input (wave-private rows): cols 0..31 = yy ----
    {
        int rowg = 16*w + (lane>>2);
        int q = lane & 3;
        int ns = chunk*NR + rowg;
        int bs = ns / NWIN, ts = ns - bs*NWIN;
        const float* gp = x + (size_t)(bs*SEQT + ts)*DDIM + 8*q;
        float4 v0 = ((const float4*)gp)[0];
        float4 v1 = ((const float4*)gp)[1];
        uint4 pk;
        pk.x = pk2(v0.x, v0.y); pk.y = pk2(v0.z, v0.w);
        pk.z = pk2(v1.x, v1.y); pk.w = pk2(v1.z, v1.w);
        *(uint4*)&bufC[rowg*64 + 16*(q ^ (rowg & 3))] = pk;
    }

    // per-lane window & current-step feature
    const int n = chunk*NR + row;
    const int b = n / NWIN, tn = n - b*NWIN;
    const float xx = x[(size_t)(b*SEQT + tn + 2)*DDIM + d];

    f4 accA[4], accB[4];

    // ---------------- L1 (K=32 MFMA + fp32 rank-1 for col 32) ----------------
    #pragma unroll
    for (int t=0;t<4;++t){
        float4 bv = *(const float4*)(bias0 + d*64 + 16*t + 4*hi);
        accA[t][0]=bv.x; accA[t][1]=bv.y; accA[t][2]=bv.z; accA[t][3]=bv.w;
    }
    {
        sh8 bfrag = *(const sh8*)&bufC[row*64 + 16*(hi ^ (nl & 3))];
        #pragma unroll
        for (int t=0;t<4;++t){
            sh8 afrag = *(const sh8*)&W0b[((16*t+nl)*32 + 8*hi)*2];
            accA[t] = __builtin_amdgcn_mfma_f32_16x16x32_bf16(afrag, bfrag, accA[t], 0,0,0);
        }
    }
    // epilogue: rank-1, act -> bufA ; t1 = deriv1.*wcol -> bufB
    {
        const float* wcolp = (const float*)(wsb + WCOL_OFF) + d*64;
        #pragma unroll
        for (int t=0;t<4;++t){
            float4 wv = *(const float4*)(wcolp + 16*t + 4*hi);
            float wc[4] = {wv.x, wv.y, wv.z, wv.w};
            float v[4], tv[4];
            #pragma unroll
            for (int r=0;r<4;++r){
                float a = fmaf(wc[r], xx, accA[t][r]);
                v[r]  = fmaxf(a, SLOPE*a);
                tv[r] = (a >= 0.f) ? wc[r] : SLOPE*wc[r];
            }
            uint2 ph; ph.x = pk2(v[0],v[1]);  ph.y = pk2(v[2],v[3]);
            *(uint2*)&bufA[row*128 + ((32*t + 8*hi) ^ rsw)] = ph;
            uint2 pt; pt.x = pk2(tv[0],tv[1]); pt.y = pk2(tv[2],tv[3]);
            *(uint2*)&bufB[row*128 + ((32*t + 8*hi) ^ rsw)] = pt;
        }
    }

    // ---------------- L2: h2 = act(W1 h1 + b1)  (bufA in-place) ----------------
    #pragma unroll
    for (int t=0;t<4;++t){
        float4 bv = *(const float4*)(bias1 + d*64 + 16*t + 4*hi);
        accA[t][0]=bv.x; accA[t][1]=bv.y; accA[t][2]=bv.z; accA[t][3]=bv.w;
    }
    #pragma unroll
    for (int ks=0; ks<2; ++ks){
        sh8 bfrag = *(const sh8*)&bufA[row*128 + ((64*ks + 16*hi) ^ rsw)];
        #pragma unroll
        for (int t=0;t<4;++t)
            accA[t] = __builtin_amdgcn_mfma_f32_16x16x32_bf16(w1f[ks][t], bfrag, accA[t], 0,0,0);
    }
    #pragma unroll
    for (int t=0;t<4;++t){
        float v[4];
        #pragma unroll
        for (int r=0;r<4;++r){
            float a = accA[t][r];
            v[r] = fmaxf(a, SLOPE*a);
            accA[t][r] = v[r];                 // keep h2 (sign carries deriv2)
        }
        uint2 ph; ph.x = pk2(v[0],v[1]); ph.y = pk2(v[2],v[3]);
        *(uint2*)&bufA[row*128 + ((32*t + 8*hi) ^ rsw)] = ph;
    }

    // ---------------- T2: t2 = d2 .* (W1 t1)  (bufB in-place) ----------------
    #pragma unroll
    for (int t=0;t<4;++t) accB[t] = (f4){0.f,0.f,0.f,0.f};
    #pragma unroll
    for (int ks=0; ks<2; ++ks){
        sh8 bfrag = *(const sh8*)&bufB[row*128 + ((64*ks + 16*hi) ^ rsw)];
        #pragma unroll
        for (int t=0;t<4;++t)
            accB[t] = __builtin_amdgcn_mfma_f32_16x16x32_bf16(w1f[ks][t], bfrag, accB[t], 0,0,0);
    }
    #pragma unroll
    for (int t=0;t<4;++t){
        float v[4];
        #pragma unroll
        for (int r=0;r<4;++r){
            float a = accB[t][r];
            v[r] = (accA[t][r] >= 0.f) ? a : SLOPE*a;   // sign(h2) == sign(a2)
        }
        uint2 pt; pt.x = pk2(v[0],v[1]); pt.y = pk2(v[2],v[3]);
        *(uint2*)&bufB[row*128 + ((32*t + 8*hi) ^ rsw)] = pt;
    }

    // ---------------- L3: h3 = act(W2 h2 + b2)  (stays in regs) ----------------
    #pragma unroll
    for (int t=0;t<4;++t){
        float4 bv = *(const float4*)(bias2 + d*64 + 16*t + 4*hi);
        accA[t][0]=bv.x; accA[t][1]=bv.y; accA[t][2]=bv.z; accA[t][3]=bv.w;
    }
    #pragma unroll
    for (int ks=0; ks<2; ++ks){
        sh8 bfrag = *(const sh8*)&bufA[row*128 + ((64*ks + 16*hi) ^ rsw)];
        #pragma unroll
        for (int t=0;t<4;++t)
            accA[t] = __builtin_amdgcn_mfma_f32_16x16x32_bf16(w2f[ks][t], bfrag, accA[t], 0,0,0);
    }
    #pragma unroll
    for (int t=0;t<4;++t)
        #pragma unroll
        for (int r=0;r<4;++r){
            float a = accA[t][r];
            accA[t][r] = fmaxf(a, SLOPE*a);    // h3 (sign carries deriv3)
        }

    // ---------------- T3: t3raw = W2 t2  (regs) ----------------
    #pragma unroll
    for (int t=0;t<4;++t) accB[t] = (f4){0.f,0.f,0.f,0.f};
    #pragma unroll
    for (int ks=0; ks<2; ++ks){
        sh8 bfrag = *(const sh8*)&bufB[row*128 + ((64*ks + 16*hi) ^ rsw)];
        #pragma unroll
        for (int t=0;t<4;++t)
            accB[t] = __builtin_amdgcn_mfma_f32_16x16x32_bf16(w2f[ks][t], bfrag, accB[t], 0,0,0);
    }

    // ---------------- head + logdet ----------------
    float res = 0.f, dres = 0.f;
    #pragma unroll
    for (int t=0;t<4;++t){
        float4 ov = *(const float4*)(Wout + d*64 + 16*t + 4*hi);
        float wo[4] = {ov.x, ov.y, ov.z, ov.w};
        #pragma unroll
        for (int r=0;r<4;++r){
            float h3 = accA[t][r];
            res = fmaf(wo[r], h3, res);
            float a = accB[t][r];
            float tv = (h3 >= 0.f) ? a : SLOPE*a;
            dres = fmaf(wo[r], tv, dres);
        }
    }
    res  += __shfl_xor(res, 16);  res  += __shfl_xor(res, 32);
    dres += __shfl_xor(dres, 16); dres += __shfl_xor(dres, 32);
    res += boutp[d];
    if (hi == 0)
        out[(size_t)n*DDIM + d] = res;

    float logabs = __logf(fabsf(dres));

    // ---------------- per-wave deterministic reduction (split by batch) ----------------
    {
        int cb0 = (chunk*NR) / NWIN;
        float v0 = (b == cb0)     ? logabs : 0.f;
        float v1 = (b == cb0 + 1) ? logabs : 0.f;
        #pragma unroll
        for (int s = 1; s < 16; s <<= 1){
            v0 += __shfl_xor(v0, s);
            v1 += __shfl_xor(v1, s);
        }
        if (lane == 0){
            red[((size_t)(chunk*4 + w)*16 + d)*2 + 0] = v0;
            red[((size_t)(chunk*4 + w)*16 + d)*2 + 1] = v1;
        }
    }
}

__global__ void final_red(const float* __restrict__ red, float* __restrict__ sld){
    __shared__ float pp[DDIM][16];
    const int b = blockIdx.x;
    const int tid = threadIdx.x;
    const int d = tid & 15, j = tid >> 4;   // j = 0..15
    float s = 0.f;
    for (int gw = j; gw < NCH*4; gw += 16){
        int chunk = gw >> 2;
        int cb0 = (chunk*NR)/NWIN;
        const float* r = red + ((size_t)gw*16 + d)*2;
        if (cb0     == b) s += r[0];
        if (cb0 + 1 == b) s += r[1];
    }
    pp[d][j] = s;
    __syncthreads();
    if (tid < DDIM){
        float a = 0.f;
        #pragma unroll
        for (int k=0;k<16;++k) a += pp[tid][k];
        pp[tid][0] = a;
    }
    __syncthreads();
    if (tid == 0){
        float a = 0.f;
        #pragma unroll
        for (int dd=0; dd<DDIM; ++dd) a += pp[dd][0];
        sld[b] = a;
    }
}

extern "C" void kernel_launch(void* const* d_in, const int* in_sizes, int n_in,
                              void* d_out, int out_size, void* d_ws, size_t ws_size,
                              hipStream_t stream) {
    const float* x    = (const float*)d_in[0];
    const float* W0   = (const float*)d_in[1];
    const float* b0   = (const float*)d_in[2];
    const float* W1   = (const float*)d_in[3];
    const float* b1   = (const float*)d_in[4];
    const float* W2   = (const float*)d_in[5];
    const float* b2   = (const float*)d_in[6];
    const float* Wout = (const float*)d_in[7];
    const float* bout = (const float*)d_in[8];
    float* out = (float*)d_out;
    unsigned char* wsb = (unsigned char*)d_ws;

    prep<<<(NPREP + 255)/256, 256, 0, stream>>>(W0, W1, W2, wsb);

    dim3 grid(NCH, DDIM);
    mlp<<<grid, 256, 0, stream>>>(x, b0, b1, b2, Wout, bout, wsb,
                                  (float*)(wsb + RED_OFF), out);

    final_red<<<NB, 256, 0, stream>>>((const float*)(wsb + RED_OFF),
                                      out + (size_t)NTOT*DDIM);
}